// Round 2
// baseline (7102.908 us; speedup 1.0000x reference)
//
#include <hip/hip_runtime.h>

// DeepSeekV3 MLA forward, MI355X gfx950.
// I/O is fp32 (reference dtypes); internal GEMM/attention math in bf16 MFMA.
// B=2 S=2048 D=2048 H=16 NOPE=128 ROPE=64 DV=128 DQK=192 QLR=1536 KVLR=512
// Workspace requirement: ~169.1 MB (region-aliased).

typedef unsigned short u16;
typedef __attribute__((ext_vector_type(8))) __bf16 bf16x8;
typedef __attribute__((ext_vector_type(4))) float f32x4;

#define DEV static __device__ __forceinline__

DEV float b2f(u16 v) { return __uint_as_float(((unsigned int)v) << 16); }
DEV u16 f2b(float f) {
  unsigned int u = __float_as_uint(f);
  u += 0x7fffu + ((u >> 16) & 1u);   // round-to-nearest-even
  return (u16)(u >> 16);
}
DEV float lo16(unsigned int w) { return __uint_as_float(w << 16); }
DEV float hi16(unsigned int w) { return __uint_as_float(w & 0xffff0000u); }

DEV float waveReduceSum(float v) {
  #pragma unroll
  for (int o = 32; o > 0; o >>= 1) v += __shfl_down(v, o, 64);
  return v;
}
DEV float waveReduceMax(float v) {
  #pragma unroll
  for (int o = 32; o > 0; o >>= 1) v = fmaxf(v, __shfl_down(v, o, 64));
  return v;
}

// ---------------- convert fp32 -> bf16 (flat) ----------------
__global__ __launch_bounds__(256)
void cvt_f32_bf16(const float* __restrict__ in, u16* __restrict__ out, int n4) {
  int i = blockIdx.x * 256 + threadIdx.x;
  if (i < n4) {
    float4 v = reinterpret_cast<const float4*>(in)[i];
    ushort4 o;
    o.x = f2b(v.x); o.y = f2b(v.y); o.z = f2b(v.z); o.w = f2b(v.w);
    reinterpret_cast<ushort4*>(out)[i] = o;
  }
}

// ---------------- transpose+convert: in f32 [R][C] -> out bf16 [C][R] ----------------
__global__ __launch_bounds__(256)
void transpose_f32_bf16(const float* __restrict__ in, u16* __restrict__ out, int R, int C) {
  __shared__ u16 tile[32][33];
  int c0 = blockIdx.x * 32, r0 = blockIdx.y * 32;
  for (int i = threadIdx.y; i < 32; i += 8)
    tile[i][threadIdx.x] = f2b(in[(size_t)(r0 + i) * C + c0 + threadIdx.x]);
  __syncthreads();
  for (int i = threadIdx.y; i < 32; i += 8)
    out[(size_t)(c0 + i) * R + r0 + threadIdx.x] = tile[threadIdx.x][i];
}

// ---------------- MFMA bt-GEMM: C[M][N] = A[M][K] * BT[N][K]^T ----------------
// 128x128 tile, 4 waves (2x2 of 64x64), BK=32, mfma_f32_16x16x32_bf16.
// LDS layout [kq][row][8]: fragment read = contiguous 16B, 2-way bank alias (free).
// M must be a multiple of 128, K a multiple of 32; N guarded.
template<int OUT_BF16>
__global__ __launch_bounds__(256)
void gemm_bt(const u16* __restrict__ A, const u16* __restrict__ BT, void* __restrict__ Cp,
             int M, int N, int K) {
  __shared__ __attribute__((aligned(16))) u16 As[4096];
  __shared__ __attribute__((aligned(16))) u16 Bs[4096];
  const int tid = threadIdx.x;
  const int lane = tid & 63;
  const int wave = tid >> 6;
  const int wm = (wave >> 1) * 64;
  const int wn = (wave & 1) * 64;
  const int q = lane >> 4;       // quad 0..3
  const int l16 = lane & 15;
  const int bm = blockIdx.y * 128;
  const int bn = blockIdx.x * 128;

  f32x4 zero = {0.f, 0.f, 0.f, 0.f};
  f32x4 acc[4][4];
  #pragma unroll
  for (int i = 0; i < 4; i++)
    #pragma unroll
    for (int j = 0; j < 4; j++) acc[i][j] = zero;

  for (int k0 = 0; k0 < K; k0 += 32) {
    #pragma unroll
    for (int i = 0; i < 2; i++) {
      int c = tid + i * 256;
      int m = c >> 2;          // 0..127
      int kq = c & 3;          // 0..3
      uint4 va = *reinterpret_cast<const uint4*>(A + (size_t)(bm + m) * K + k0 + kq * 8);
      *reinterpret_cast<uint4*>(As + (kq * 128 + m) * 8) = va;
      uint4 vb;
      if (bn + m < N)
        vb = *reinterpret_cast<const uint4*>(BT + (size_t)(bn + m) * K + k0 + kq * 8);
      else
        vb = make_uint4(0u, 0u, 0u, 0u);
      *reinterpret_cast<uint4*>(Bs + (kq * 128 + m) * 8) = vb;
    }
    __syncthreads();
    bf16x8 af[4], bfr[4];
    #pragma unroll
    for (int t = 0; t < 4; t++) {
      af[t]  = *reinterpret_cast<const bf16x8*>(As + (q * 128 + wm + t * 16 + l16) * 8);
      bfr[t] = *reinterpret_cast<const bf16x8*>(Bs + (q * 128 + wn + t * 16 + l16) * 8);
    }
    #pragma unroll
    for (int mt = 0; mt < 4; mt++)
      #pragma unroll
      for (int nt = 0; nt < 4; nt++)
        acc[mt][nt] = __builtin_amdgcn_mfma_f32_16x16x32_bf16(af[mt], bfr[nt], acc[mt][nt], 0, 0, 0);
    __syncthreads();
  }

  // C/D layout: col = lane&15, row = (lane>>4)*4 + reg
  float* Cf = (float*)Cp;
  u16* Cb = (u16*)Cp;
  #pragma unroll
  for (int mt = 0; mt < 4; mt++) {
    #pragma unroll
    for (int nt = 0; nt < 4; nt++) {
      int col = bn + wn + nt * 16 + l16;
      if (col < N) {
        int row0 = bm + wm + mt * 16 + q * 4;
        #pragma unroll
        for (int r = 0; r < 4; r++) {
          size_t idx = (size_t)(row0 + r) * N + col;
          float v = acc[mt][nt][r];
          if (OUT_BF16) Cb[idx] = f2b(v); else Cf[idx] = v;
        }
      }
    }
  }
}

// ---------------- rmsnorm rows: fp32 in -> bf16 out ----------------
__global__ __launch_bounds__(256)
void rmsnorm_rows(const float* __restrict__ in, u16* __restrict__ out, int C) {
  int row = blockIdx.x;
  const float* x = in + (size_t)row * C;
  float ss = 0.f;
  for (int i = threadIdx.x; i < C; i += 256) { float v = x[i]; ss += v * v; }
  ss = waveReduceSum(ss);
  __shared__ float red[4];
  __shared__ float s_scale;
  int lane = threadIdx.x & 63, wid = threadIdx.x >> 6;
  if (lane == 0) red[wid] = ss;
  __syncthreads();
  if (threadIdx.x == 0)
    s_scale = rsqrtf((red[0] + red[1] + red[2] + red[3]) / (float)C + 1e-5f);
  __syncthreads();
  float sc = s_scale;
  u16* o = out + (size_t)row * C;
  for (int i = threadIdx.x; i < C; i += 256) o[i] = f2b(x[i] * sc);
}

// ---------------- rope + pack Q: q2 bf16 [B*S][H*192] -> Q bf16 [B*H][S][192] ----------------
// Q row = [roped q_rope(64) | q_nope(128)];  fc/fs are fp32 [S][32]
__global__ __launch_bounds__(256)
void rope_pack_q(const u16* __restrict__ q2, const float* __restrict__ fc, const float* __restrict__ fs,
                 u16* __restrict__ Q) {
  int bs = blockIdx.x;
  int b = bs >> 11, s = bs & 2047;
  __shared__ float c[32], sn[32];
  if (threadIdx.x < 32) {
    c[threadIdx.x] = fc[s * 32 + threadIdx.x];
    sn[threadIdx.x] = fs[s * 32 + threadIdx.x];
  }
  __syncthreads();
  const u16* qrow = q2 + (size_t)bs * 3072;
  for (int t = threadIdx.x; t < 512; t += 256) {
    int h = t >> 5, i = t & 31;
    float x0 = b2f(qrow[h * 192 + 128 + 2 * i]);
    float x1 = b2f(qrow[h * 192 + 128 + 2 * i + 1]);
    size_t base = ((size_t)(b * 16 + h) * 2048 + s) * 192;
    Q[base + 2 * i]     = f2b(x0 * c[i] - x1 * sn[i]);
    Q[base + 2 * i + 1] = f2b(x0 * sn[i] + x1 * c[i]);
  }
  for (int t = threadIdx.x; t < 2048; t += 256) {
    int h = t >> 7, j = t & 127;
    Q[((size_t)(b * 16 + h) * 2048 + s) * 192 + 64 + j] = qrow[h * 192 + j];
  }
}

// ---------------- kv split: t3 fp32 [B*S][576] -> rmsnorm(kvl) bf16 + roped k_rope bf16 ----------------
__global__ __launch_bounds__(256)
void kv_split(const float* __restrict__ t3, const float* __restrict__ fc, const float* __restrict__ fs,
              u16* __restrict__ kvl, u16* __restrict__ krope) {
  int row = blockIdx.x;
  int s = row & 2047;
  const float* x = t3 + (size_t)row * 576;
  float ss = 0.f;
  for (int i = threadIdx.x; i < 512; i += 256) { float v = x[i]; ss += v * v; }
  ss = waveReduceSum(ss);
  __shared__ float red[4];
  __shared__ float s_scale;
  int lane = threadIdx.x & 63, wid = threadIdx.x >> 6;
  if (lane == 0) red[wid] = ss;
  __syncthreads();
  if (threadIdx.x == 0)
    s_scale = rsqrtf((red[0] + red[1] + red[2] + red[3]) * (1.0f / 512.0f) + 1e-5f);
  __syncthreads();
  float sc = s_scale;
  for (int i = threadIdx.x; i < 512; i += 256) kvl[(size_t)row * 512 + i] = f2b(x[i] * sc);
  if (threadIdx.x < 32) {
    int i = threadIdx.x;
    float cc = fc[s * 32 + i], sn = fs[s * 32 + i];
    float x0 = x[512 + 2 * i], x1 = x[512 + 2 * i + 1];
    krope[(size_t)row * 64 + 2 * i]     = f2b(x0 * cc - x1 * sn);
    krope[(size_t)row * 64 + 2 * i + 1] = f2b(x0 * sn + x1 * cc);
  }
}

// ---------------- assemble K bf16 [B*H][S][192], V bf16 [B*H][S][128] ----------------
__global__ __launch_bounds__(256)
void assemble_kv(const u16* __restrict__ kv, const u16* __restrict__ krope,
                 u16* __restrict__ K, u16* __restrict__ V) {
  int bs = blockIdx.x;
  int b = bs >> 11, s = bs & 2047;
  const u16* kvrow = kv + (size_t)bs * 4096;
  const u16* kr = krope + (size_t)bs * 64;
  for (int t = threadIdx.x; t < 1024; t += 256) {
    int h = t >> 6, d = t & 63;
    K[((size_t)(b * 16 + h) * 2048 + s) * 192 + d] = kr[d];
  }
  for (int t = threadIdx.x; t < 2048; t += 256) {
    int h = t >> 7, j = t & 127;
    K[((size_t)(b * 16 + h) * 2048 + s) * 192 + 64 + j] = kvrow[h * 128 + j];
    V[((size_t)(b * 16 + h) * 2048 + s) * 128 + j] = kvrow[2048 + h * 128 + j];
  }
}

// ---------------- attention: one block per (b,h,q), scores in LDS ----------------
__global__ __launch_bounds__(256)
void attn_kernel(const u16* __restrict__ Q, const u16* __restrict__ K, const u16* __restrict__ V,
                 u16* __restrict__ O) {
  const int qi = blockIdx.x;
  const int bh = blockIdx.y;
  const int b = bh >> 4, h = bh & 15;
  const int nk = qi + 1;
  const int tid = threadIdx.x;
  __shared__ float qf[192];
  __shared__ float sc[2048];
  __shared__ float vacc[8][128];
  __shared__ float red[4];
  __shared__ float s_inv;

  if (tid < 192) qf[tid] = b2f(Q[((size_t)bh * 2048 + qi) * 192 + tid]);
  __syncthreads();

  const float scale = 0.07216878364870323f;  // 1/sqrt(192)
  // QK^T: up to 8 keys per thread, d-chunked so qf LDS reads amortize 8x
  float accv[8];
  #pragma unroll
  for (int j = 0; j < 8; j++) accv[j] = 0.f;
  const u16* Kbase = K + (size_t)bh * 2048 * 192;
  for (int cI = 0; cI < 24; cI++) {
    float qq[8];
    #pragma unroll
    for (int j = 0; j < 8; j++) qq[j] = qf[cI * 8 + j];
    #pragma unroll
    for (int j = 0; j < 8; j++) {
      int kk = tid + 256 * j;
      if (kk < nk) {
        uint4 u = *reinterpret_cast<const uint4*>(Kbase + (size_t)kk * 192 + cI * 8);
        accv[j] += qq[0] * lo16(u.x) + qq[1] * hi16(u.x)
                 + qq[2] * lo16(u.y) + qq[3] * hi16(u.y)
                 + qq[4] * lo16(u.z) + qq[5] * hi16(u.z)
                 + qq[6] * lo16(u.w) + qq[7] * hi16(u.w);
      }
    }
  }
  #pragma unroll
  for (int j = 0; j < 8; j++) {
    int kk = tid + 256 * j;
    if (kk < nk) sc[kk] = accv[j] * scale;
  }
  __syncthreads();

  int lane = tid & 63, wid = tid >> 6;
  float lmax = -1e30f;
  for (int kk = tid; kk < nk; kk += 256) lmax = fmaxf(lmax, sc[kk]);
  lmax = waveReduceMax(lmax);
  if (lane == 0) red[wid] = lmax;
  __syncthreads();
  float M = fmaxf(fmaxf(red[0], red[1]), fmaxf(red[2], red[3]));
  __syncthreads();
  float lsum = 0.f;
  for (int kk = tid; kk < nk; kk += 256) {
    float e = __expf(sc[kk] - M);
    sc[kk] = e;
    lsum += e;
  }
  lsum = waveReduceSum(lsum);
  if (lane == 0) red[wid] = lsum;
  __syncthreads();
  if (tid == 0) s_inv = 1.0f / (red[0] + red[1] + red[2] + red[3]);
  __syncthreads();
  float inv = s_inv;

  // PV: thread -> (part = tid>>5 of 8, 4 d's at dg*4), coalesced V rows
  int dg = tid & 31, part = tid >> 5;
  float a0 = 0.f, a1 = 0.f, a2 = 0.f, a3 = 0.f;
  const u16* Vbase = V + (size_t)bh * 2048 * 128 + dg * 4;
  for (int kk = part; kk < nk; kk += 8) {
    uint2 u = *reinterpret_cast<const uint2*>(Vbase + (size_t)kk * 128);
    float p = sc[kk];
    a0 += p * lo16(u.x); a1 += p * hi16(u.x);
    a2 += p * lo16(u.y); a3 += p * hi16(u.y);
  }
  vacc[part][dg * 4 + 0] = a0; vacc[part][dg * 4 + 1] = a1;
  vacc[part][dg * 4 + 2] = a2; vacc[part][dg * 4 + 3] = a3;
  __syncthreads();
  if (tid < 128) {
    float o = 0.f;
    #pragma unroll
    for (int p = 0; p < 8; p++) o += vacc[p][tid];
    O[((size_t)b * 2048 + qi) * 2048 + h * 128 + tid] = f2b(o * inv);
  }
}

// ---------------- launch ----------------
extern "C" void kernel_launch(void* const* d_in, const int* in_sizes, int n_in,
                              void* d_out, int out_size, void* d_ws, size_t ws_size,
                              hipStream_t stream) {
  (void)in_sizes; (void)n_in; (void)out_size; (void)ws_size;
  const float* hs   = (const float*)d_in[0];
  // d_in[1] sequence_mask: all true, ignored
  const float* fc   = (const float*)d_in[2];
  const float* fs   = (const float*)d_in[3];
  const float* Wqd  = (const float*)d_in[4];
  const float* Wkvd = (const float*)d_in[5];
  const float* Wqu  = (const float*)d_in[6];
  const float* Wkvu = (const float*)d_in[7];
  const float* Wo   = (const float*)d_in[8];

  char* ws = (char*)d_ws;
  size_t off = 0;
  auto alloc = [&](size_t bytes) { size_t o = off; off += (bytes + 255) & ~(size_t)255; return o; };
  const size_t oHS   = alloc(16777216);  // hs_bf bf16 [4096][2048]
  const size_t oRA   = alloc(25165824);  // t1 f32 [4096,1536] -> t3 f32 [4096,576] -> V bf16
  const size_t oRB   = alloc(25165824);  // q2 bf16 [4096,3072] -> K bf16
  const size_t oRC   = alloc(12582912);  // qlat bf16 [4096,1536] -> kvl bf16 + krope bf16
  const size_t oRD   = alloc(25165824);  // Q bf16 [B*H][S][192]
  const size_t oRE   = alloc(33554432);  // kv bf16 [4096,4096] -> attn_out bf16 [4096,2048]
  const size_t oWqdT  = alloc(6291456);
  const size_t oWkvdT = alloc(2359296);
  const size_t oWquT  = alloc(9437184);
  const size_t oWkvuT = alloc(4194304);
  const size_t oWoT   = alloc(8388608);

  u16* hs_bf = (u16*)(ws + oHS);
  float* t1 = (float*)(ws + oRA);
  float* t3 = (float*)(ws + oRA);
  u16* Vb   = (u16*)(ws + oRA);
  u16* q2   = (u16*)(ws + oRB);
  u16* Kb   = (u16*)(ws + oRB);
  u16* qlat = (u16*)(ws + oRC);
  u16* kvl  = (u16*)(ws + oRC);
  u16* krope = (u16*)(ws + oRC + 4194304);
  u16* Qb   = (u16*)(ws + oRD);
  u16* kvb  = (u16*)(ws + oRE);
  u16* attn_out = (u16*)(ws + oRE);
  u16* WqdT  = (u16*)(ws + oWqdT);
  u16* WkvdT = (u16*)(ws + oWkvdT);
  u16* WquT  = (u16*)(ws + oWquT);
  u16* WkvuT = (u16*)(ws + oWkvuT);
  u16* WoT   = (u16*)(ws + oWoT);

  // input conversion
  cvt_f32_bf16<<<8192, 256, 0, stream>>>(hs, hs_bf, 2097152);
  dim3 tb(32, 8);
  transpose_f32_bf16<<<dim3(48, 64), tb, 0, stream>>>(Wqd, WqdT, 2048, 1536);
  transpose_f32_bf16<<<dim3(18, 64), tb, 0, stream>>>(Wkvd, WkvdT, 2048, 576);
  transpose_f32_bf16<<<dim3(96, 48), tb, 0, stream>>>(Wqu, WquT, 1536, 3072);
  transpose_f32_bf16<<<dim3(128, 16), tb, 0, stream>>>(Wkvu, WkvuT, 512, 4096);
  transpose_f32_bf16<<<dim3(64, 64), tb, 0, stream>>>(Wo, WoT, 2048, 2048);

  // q path
  gemm_bt<0><<<dim3(12, 32), 256, 0, stream>>>(hs_bf, WqdT, t1, 4096, 1536, 2048);
  rmsnorm_rows<<<4096, 256, 0, stream>>>(t1, qlat, 1536);
  gemm_bt<1><<<dim3(24, 32), 256, 0, stream>>>(qlat, WquT, q2, 4096, 3072, 1536);
  rope_pack_q<<<4096, 256, 0, stream>>>(q2, fc, fs, Qb);
  // kv path
  gemm_bt<0><<<dim3(5, 32), 256, 0, stream>>>(hs_bf, WkvdT, t3, 4096, 576, 2048);
  kv_split<<<4096, 256, 0, stream>>>(t3, fc, fs, kvl, krope);
  gemm_bt<1><<<dim3(32, 32), 256, 0, stream>>>(kvl, WkvuT, kvb, 4096, 4096, 512);
  assemble_kv<<<4096, 256, 0, stream>>>(kvb, krope, Kb, Vb);
  // attention
  attn_kernel<<<dim3(2048, 32), 256, 0, stream>>>(Qb, Kb, Vb, attn_out);
  // output projection (fp32 out)
  gemm_bt<0><<<dim3(16, 32), 256, 0, stream>>>(attn_out, WoT, (float*)d_out, 4096, 2048, 2048);
}

// Round 3
// 660.951 us; speedup vs baseline: 10.7465x; 10.7465x over previous
//
#include <hip/hip_runtime.h>
#include <math.h>

// DeepSeekV3 MLA forward, MI355X gfx950.
// I/O fp32; internal GEMM/attention math bf16 MFMA. Flash attention (MFMA).
// B=2 S=2048 D=2048 H=16 NOPE=128 ROPE=64 DV=128 DQK=192 QLR=1536 KVLR=512

typedef unsigned short u16;
typedef __attribute__((ext_vector_type(8))) __bf16 bf16x8;
typedef __attribute__((ext_vector_type(4))) float f32x4;

#define DEV static __device__ __forceinline__

DEV float b2f(u16 v) { return __uint_as_float(((unsigned int)v) << 16); }
DEV u16 f2b(float f) {
  unsigned int u = __float_as_uint(f);
  u += 0x7fffu + ((u >> 16) & 1u);   // round-to-nearest-even
  return (u16)(u >> 16);
}

DEV float waveReduceSum(float v) {
  #pragma unroll
  for (int o = 32; o > 0; o >>= 1) v += __shfl_down(v, o, 64);
  return v;
}

// async global->LDS, 16B per lane; LDS dest = wave-uniform base + lane*16
DEV void gld16(const u16* g, u16* l) {
  __builtin_amdgcn_global_load_lds((const __attribute__((address_space(1))) void*)g,
                                   (__attribute__((address_space(3))) void*)l, 16, 0, 0);
}

// ---------------- convert fp32 -> bf16 (flat) ----------------
__global__ __launch_bounds__(256)
void cvt_f32_bf16(const float* __restrict__ in, u16* __restrict__ out, int n4) {
  int i = blockIdx.x * 256 + threadIdx.x;
  if (i < n4) {
    float4 v = reinterpret_cast<const float4*>(in)[i];
    ushort4 o;
    o.x = f2b(v.x); o.y = f2b(v.y); o.z = f2b(v.z); o.w = f2b(v.w);
    reinterpret_cast<ushort4*>(out)[i] = o;
  }
}

// ---------------- transpose+convert: in f32 [R][C] -> out bf16 [C][R] ----------------
__global__ __launch_bounds__(256)
void transpose_f32_bf16(const float* __restrict__ in, u16* __restrict__ out, int R, int C) {
  __shared__ u16 tile[32][33];
  int c0 = blockIdx.x * 32, r0 = blockIdx.y * 32;
  for (int i = threadIdx.y; i < 32; i += 8)
    tile[i][threadIdx.x] = f2b(in[(size_t)(r0 + i) * C + c0 + threadIdx.x]);
  __syncthreads();
  for (int i = threadIdx.y; i < 32; i += 8)
    out[(size_t)(c0 + i) * R + r0 + threadIdx.x] = tile[threadIdx.x][i];
}

// ---------------- MFMA bt-GEMM: C[M][N] = A[M][K] * BT[N][K]^T ----------------
template<int OUT_BF16>
__global__ __launch_bounds__(256)
void gemm_bt(const u16* __restrict__ A, const u16* __restrict__ BT, void* __restrict__ Cp,
             int M, int N, int K) {
  __shared__ __attribute__((aligned(16))) u16 As[4096];
  __shared__ __attribute__((aligned(16))) u16 Bs[4096];
  const int tid = threadIdx.x;
  const int lane = tid & 63;
  const int wave = tid >> 6;
  const int wm = (wave >> 1) * 64;
  const int wn = (wave & 1) * 64;
  const int q = lane >> 4;
  const int l16 = lane & 15;
  const int bm = blockIdx.y * 128;
  const int bn = blockIdx.x * 128;

  f32x4 zero = {0.f, 0.f, 0.f, 0.f};
  f32x4 acc[4][4];
  #pragma unroll
  for (int i = 0; i < 4; i++)
    #pragma unroll
    for (int j = 0; j < 4; j++) acc[i][j] = zero;

  for (int k0 = 0; k0 < K; k0 += 32) {
    #pragma unroll
    for (int i = 0; i < 2; i++) {
      int c = tid + i * 256;
      int m = c >> 2;
      int kq = c & 3;
      uint4 va = *reinterpret_cast<const uint4*>(A + (size_t)(bm + m) * K + k0 + kq * 8);
      *reinterpret_cast<uint4*>(As + (kq * 128 + m) * 8) = va;
      uint4 vb;
      if (bn + m < N)
        vb = *reinterpret_cast<const uint4*>(BT + (size_t)(bn + m) * K + k0 + kq * 8);
      else
        vb = make_uint4(0u, 0u, 0u, 0u);
      *reinterpret_cast<uint4*>(Bs + (kq * 128 + m) * 8) = vb;
    }
    __syncthreads();
    bf16x8 af[4], bfr[4];
    #pragma unroll
    for (int t = 0; t < 4; t++) {
      af[t]  = *reinterpret_cast<const bf16x8*>(As + (q * 128 + wm + t * 16 + l16) * 8);
      bfr[t] = *reinterpret_cast<const bf16x8*>(Bs + (q * 128 + wn + t * 16 + l16) * 8);
    }
    #pragma unroll
    for (int mt = 0; mt < 4; mt++)
      #pragma unroll
      for (int nt = 0; nt < 4; nt++)
        acc[mt][nt] = __builtin_amdgcn_mfma_f32_16x16x32_bf16(af[mt], bfr[nt], acc[mt][nt], 0, 0, 0);
    __syncthreads();
  }

  float* Cf = (float*)Cp;
  u16* Cb = (u16*)Cp;
  #pragma unroll
  for (int mt = 0; mt < 4; mt++) {
    #pragma unroll
    for (int nt = 0; nt < 4; nt++) {
      int col = bn + wn + nt * 16 + l16;
      if (col < N) {
        int row0 = bm + wm + mt * 16 + q * 4;
        #pragma unroll
        for (int r = 0; r < 4; r++) {
          size_t idx = (size_t)(row0 + r) * N + col;
          float v = acc[mt][nt][r];
          if (OUT_BF16) Cb[idx] = f2b(v); else Cf[idx] = v;
        }
      }
    }
  }
}

// ---------------- rmsnorm rows: fp32 in -> bf16 out ----------------
__global__ __launch_bounds__(256)
void rmsnorm_rows(const float* __restrict__ in, u16* __restrict__ out, int C) {
  int row = blockIdx.x;
  const float* x = in + (size_t)row * C;
  float ss = 0.f;
  for (int i = threadIdx.x; i < C; i += 256) { float v = x[i]; ss += v * v; }
  ss = waveReduceSum(ss);
  __shared__ float red[4];
  __shared__ float s_scale;
  int lane = threadIdx.x & 63, wid = threadIdx.x >> 6;
  if (lane == 0) red[wid] = ss;
  __syncthreads();
  if (threadIdx.x == 0)
    s_scale = rsqrtf((red[0] + red[1] + red[2] + red[3]) / (float)C + 1e-5f);
  __syncthreads();
  float sc = s_scale;
  u16* o = out + (size_t)row * C;
  for (int i = threadIdx.x; i < C; i += 256) o[i] = f2b(x[i] * sc);
}

// ---------------- rope + pack Q: q2 bf16 [B*S][H*192] -> Q bf16 [B*H][S][192] ----------------
__global__ __launch_bounds__(256)
void rope_pack_q(const u16* __restrict__ q2, const float* __restrict__ fc, const float* __restrict__ fs,
                 u16* __restrict__ Q) {
  int bs = blockIdx.x;
  int b = bs >> 11, s = bs & 2047;
  __shared__ float c[32], sn[32];
  if (threadIdx.x < 32) {
    c[threadIdx.x] = fc[s * 32 + threadIdx.x];
    sn[threadIdx.x] = fs[s * 32 + threadIdx.x];
  }
  __syncthreads();
  const u16* qrow = q2 + (size_t)bs * 3072;
  for (int t = threadIdx.x; t < 512; t += 256) {
    int h = t >> 5, i = t & 31;
    float x0 = b2f(qrow[h * 192 + 128 + 2 * i]);
    float x1 = b2f(qrow[h * 192 + 128 + 2 * i + 1]);
    size_t base = ((size_t)(b * 16 + h) * 2048 + s) * 192;
    Q[base + 2 * i]     = f2b(x0 * c[i] - x1 * sn[i]);
    Q[base + 2 * i + 1] = f2b(x0 * sn[i] + x1 * c[i]);
  }
  for (int t = threadIdx.x; t < 2048; t += 256) {
    int h = t >> 7, j = t & 127;
    Q[((size_t)(b * 16 + h) * 2048 + s) * 192 + 64 + j] = qrow[h * 192 + j];
  }
}

// ---------------- kv split ----------------
__global__ __launch_bounds__(256)
void kv_split(const float* __restrict__ t3, const float* __restrict__ fc, const float* __restrict__ fs,
              u16* __restrict__ kvl, u16* __restrict__ krope) {
  int row = blockIdx.x;
  int s = row & 2047;
  const float* x = t3 + (size_t)row * 576;
  float ss = 0.f;
  for (int i = threadIdx.x; i < 512; i += 256) { float v = x[i]; ss += v * v; }
  ss = waveReduceSum(ss);
  __shared__ float red[4];
  __shared__ float s_scale;
  int lane = threadIdx.x & 63, wid = threadIdx.x >> 6;
  if (lane == 0) red[wid] = ss;
  __syncthreads();
  if (threadIdx.x == 0)
    s_scale = rsqrtf((red[0] + red[1] + red[2] + red[3]) * (1.0f / 512.0f) + 1e-5f);
  __syncthreads();
  float sc = s_scale;
  for (int i = threadIdx.x; i < 512; i += 256) kvl[(size_t)row * 512 + i] = f2b(x[i] * sc);
  if (threadIdx.x < 32) {
    int i = threadIdx.x;
    float cc = fc[s * 32 + i], sn = fs[s * 32 + i];
    float x0 = x[512 + 2 * i], x1 = x[512 + 2 * i + 1];
    krope[(size_t)row * 64 + 2 * i]     = f2b(x0 * cc - x1 * sn);
    krope[(size_t)row * 64 + 2 * i + 1] = f2b(x0 * sn + x1 * cc);
  }
}

// ---------------- assemble K chunked + V transposed chunked ----------------
// Kc[bh][kq 0..23][s 2048][8]  (dims kq*8..+7 of [rope64|nope128])
// Vt[bh][ks 0..255][dv 128][8] (keys ks*8..+7)
__global__ __launch_bounds__(256)
void assemble_kv2(const u16* __restrict__ kvb, const u16* __restrict__ krope,
                  u16* __restrict__ Kc, u16* __restrict__ Vt) {
  int ks = blockIdx.x;   // 0..255
  int bh = blockIdx.y;   // 0..31
  int b = bh >> 4, h = bh & 15;
  int t = threadIdx.x;
  if (t < 192) {
    int kq = t >> 3, sl = t & 7;
    int s = ks * 8 + sl;
    size_t bs = (size_t)(b * 2048 + s);
    uint4 v;
    if (kq < 8) v = *reinterpret_cast<const uint4*>(krope + bs * 64 + kq * 8);
    else        v = *reinterpret_cast<const uint4*>(kvb + bs * 4096 + h * 128 + (kq - 8) * 8);
    *reinterpret_cast<uint4*>(Kc + (((size_t)bh * 24 + kq) * 2048 + s) * 8) = v;
  }
  if (t < 128) {
    int dv = t;
    u16 tmp[8];
    #pragma unroll
    for (int j = 0; j < 8; j++) {
      int s = ks * 8 + j;
      tmp[j] = kvb[(size_t)(b * 2048 + s) * 4096 + 2048 + h * 128 + dv];
    }
    *reinterpret_cast<uint4*>(Vt + (((size_t)bh * 256 + ks) * 128 + dv) * 8) = *reinterpret_cast<uint4*>(tmp);
  }
}

// ---------------- MFMA flash attention ----------------
// grid (16, 32): qtile = 15 - blockIdx.x (long blocks first), bh = blockIdx.y
// block = 256 threads = 4 waves; wave owns 32 q-rows; K-tile = 64 keys.
__global__ __launch_bounds__(256, 2)
void flash_attn(const u16* __restrict__ Q, const u16* __restrict__ Kc,
                const u16* __restrict__ Vt, u16* __restrict__ O) {
  __shared__ __attribute__((aligned(16))) u16 Ks[24 * 64 * 8];   // 24.5 KB [kq][key][8]
  __shared__ __attribute__((aligned(16))) u16 Vs[8 * 128 * 8];   // 16 KB  [kc][dv][8]
  __shared__ __attribute__((aligned(16))) u16 Ps[4 * 32 * 72];   // 18 KB  per-wave P, row stride 72

  const int qtile = 15 - blockIdx.x;
  const int bh = blockIdx.y;
  const int b = bh >> 4, h = bh & 15;
  const int tid = threadIdx.x, lane = tid & 63, wave = tid >> 6;
  const int quad = lane >> 4, l16 = lane & 15;
  const int q0 = qtile * 128;
  const float scale = 0.07216878364870323f;  // 1/sqrt(192)

  // Q fragments in registers: qf[mt][kc], rows q0 + wave*32 + mt*16 + l16
  bf16x8 qf[2][6];
  #pragma unroll
  for (int mt = 0; mt < 2; mt++) {
    int qrow = q0 + wave * 32 + mt * 16 + l16;
    const u16* qp = Q + ((size_t)bh * 2048 + qrow) * 192 + quad * 8;
    #pragma unroll
    for (int kc = 0; kc < 6; kc++)
      qf[mt][kc] = *reinterpret_cast<const bf16x8*>(qp + kc * 32);
  }

  f32x4 zero = {0.f, 0.f, 0.f, 0.f};
  f32x4 oacc[2][8];
  float m_run[2][4], l_run[2][4];
  #pragma unroll
  for (int mt = 0; mt < 2; mt++) {
    #pragma unroll
    for (int nt = 0; nt < 8; nt++) oacc[mt][nt] = zero;
    #pragma unroll
    for (int r = 0; r < 4; r++) { m_run[mt][r] = -INFINITY; l_run[mt][r] = 0.f; }
  }

  u16* PsW = Ps + wave * 32 * 72;
  const int nk = (qtile + 1) * 128;

  for (int k0 = 0; k0 < nk; k0 += 64) {
    __syncthreads();   // prior iteration's LDS reads complete
    // stage K-tile: wave handles kq = wave*6 .. wave*6+5; lane -> key row
    #pragma unroll
    for (int ii = 0; ii < 6; ii++) {
      int kq = wave * 6 + ii;
      gld16(Kc + (((size_t)bh * 24 + kq) * 2048 + k0 + lane) * 8, Ks + kq * 64 * 8);
    }
    // stage V-tile: 16 chunks of (64 dv x 16B); wave handles 4
    #pragma unroll
    for (int jj = 0; jj < 4; jj++) {
      int vc = wave * 4 + jj;
      int kc = vc >> 1, dvh = vc & 1;
      gld16(Vt + (((size_t)bh * 256 + (k0 >> 3) + kc) * 128 + dvh * 64 + lane) * 8,
            Vs + (kc * 128 + dvh * 64) * 8);
    }
    __syncthreads();   // staging visible (vmcnt drained before barrier)

    // QK^T: S = Q Ktile^T
    f32x4 sacc[2][4];
    #pragma unroll
    for (int mt = 0; mt < 2; mt++)
      #pragma unroll
      for (int nt = 0; nt < 4; nt++) sacc[mt][nt] = zero;
    #pragma unroll
    for (int kc = 0; kc < 6; kc++) {
      bf16x8 kb[4];
      #pragma unroll
      for (int nt = 0; nt < 4; nt++)
        kb[nt] = *reinterpret_cast<const bf16x8*>(Ks + ((kc * 4 + quad) * 64 + nt * 16 + l16) * 8);
      #pragma unroll
      for (int mt = 0; mt < 2; mt++)
        #pragma unroll
        for (int nt = 0; nt < 4; nt++)
          sacc[mt][nt] = __builtin_amdgcn_mfma_f32_16x16x32_bf16(qf[mt][kc], kb[nt], sacc[mt][nt], 0, 0, 0);
    }

    // online softmax (per-wave; rows quad*4+r in tile mt; cols l16 in tile nt)
    #pragma unroll
    for (int mt = 0; mt < 2; mt++) {
      #pragma unroll
      for (int r = 0; r < 4; r++) {
        int qrow_g = q0 + wave * 32 + mt * 16 + quad * 4 + r;
        float sv[4];
        #pragma unroll
        for (int nt = 0; nt < 4; nt++) {
          int key = k0 + nt * 16 + l16;
          float v = sacc[mt][nt][r] * scale;
          sv[nt] = (key <= qrow_g) ? v : -1e30f;
        }
        float mx = fmaxf(fmaxf(sv[0], sv[1]), fmaxf(sv[2], sv[3]));
        #pragma unroll
        for (int d = 1; d < 16; d <<= 1) mx = fmaxf(mx, __shfl_xor(mx, d, 64));
        float mold = m_run[mt][r];
        float mnew = fmaxf(mold, mx);
        float alpha = __expf(mold - mnew);
        m_run[mt][r] = mnew;
        float psum = 0.f;
        #pragma unroll
        for (int nt = 0; nt < 4; nt++) {
          float p = __expf(sv[nt] - mnew);
          psum += p;
          PsW[(mt * 16 + quad * 4 + r) * 72 + nt * 16 + l16] = f2b(p);
        }
        #pragma unroll
        for (int d = 1; d < 16; d <<= 1) psum += __shfl_xor(psum, d, 64);
        l_run[mt][r] = l_run[mt][r] * alpha + psum;
        #pragma unroll
        for (int nt = 0; nt < 8; nt++) oacc[mt][nt][r] *= alpha;
      }
    }

    // PV: O += P Vtile  (P read back in A-layout from wave-private LDS)
    #pragma unroll
    for (int kcp = 0; kcp < 2; kcp++) {
      bf16x8 pa[2];
      #pragma unroll
      for (int mt = 0; mt < 2; mt++)
        pa[mt] = *reinterpret_cast<const bf16x8*>(PsW + (mt * 16 + l16) * 72 + kcp * 32 + quad * 8);
      #pragma unroll
      for (int nt = 0; nt < 8; nt++) {
        bf16x8 vb = *reinterpret_cast<const bf16x8*>(Vs + ((kcp * 4 + quad) * 128 + nt * 16 + l16) * 8);
        #pragma unroll
        for (int mt = 0; mt < 2; mt++)
          oacc[mt][nt] = __builtin_amdgcn_mfma_f32_16x16x32_bf16(pa[mt], vb, oacc[mt][nt], 0, 0, 0);
      }
    }
  }

  // epilogue: O[b][s][h*128+dv] bf16
  #pragma unroll
  for (int mt = 0; mt < 2; mt++) {
    float inv[4];
    #pragma unroll
    for (int r = 0; r < 4; r++) inv[r] = 1.0f / l_run[mt][r];
    #pragma unroll
    for (int nt = 0; nt < 8; nt++) {
      #pragma unroll
      for (int r = 0; r < 4; r++) {
        int s = q0 + wave * 32 + mt * 16 + quad * 4 + r;
        O[((size_t)b * 2048 + s) * 2048 + h * 128 + nt * 16 + l16] = f2b(oacc[mt][nt][r] * inv[r]);
      }
    }
  }
}

// ---------------- launch ----------------
extern "C" void kernel_launch(void* const* d_in, const int* in_sizes, int n_in,
                              void* d_out, int out_size, void* d_ws, size_t ws_size,
                              hipStream_t stream) {
  (void)in_sizes; (void)n_in; (void)out_size; (void)ws_size;
  const float* hs   = (const float*)d_in[0];
  const float* fc   = (const float*)d_in[2];
  const float* fs   = (const float*)d_in[3];
  const float* Wqd  = (const float*)d_in[4];
  const float* Wkvd = (const float*)d_in[5];
  const float* Wqu  = (const float*)d_in[6];
  const float* Wkvu = (const float*)d_in[7];
  const float* Wo   = (const float*)d_in[8];

  char* ws = (char*)d_ws;
  size_t off = 0;
  auto alloc = [&](size_t bytes) { size_t o = off; off += (bytes + 255) & ~(size_t)255; return o; };
  const size_t oHS   = alloc(16777216);  // hs_bf bf16 [4096][2048]
  const size_t oRA   = alloc(25165824);  // t1 f32 -> t3 f32 -> Vt bf16 (16.8MB)
  const size_t oRB   = alloc(25165824);  // q2 bf16 -> Kc bf16 (25.2MB exact)
  const size_t oRC   = alloc(12582912);  // qlat -> kvl + krope
  const size_t oRD   = alloc(25165824);  // Q bf16 [B*H][S][192]
  const size_t oRE   = alloc(33554432);  // kvb bf16 [4096,4096] -> attn_out bf16 [4096,2048]
  const size_t oWqdT  = alloc(6291456);
  const size_t oWkvdT = alloc(2359296);
  const size_t oWquT  = alloc(9437184);
  const size_t oWkvuT = alloc(4194304);
  const size_t oWoT   = alloc(8388608);

  u16* hs_bf = (u16*)(ws + oHS);
  float* t1 = (float*)(ws + oRA);
  float* t3 = (float*)(ws + oRA);
  u16* Vt   = (u16*)(ws + oRA);
  u16* q2   = (u16*)(ws + oRB);
  u16* Kc   = (u16*)(ws + oRB);
  u16* qlat = (u16*)(ws + oRC);
  u16* kvl  = (u16*)(ws + oRC);
  u16* krope = (u16*)(ws + oRC + 4194304);
  u16* Qb   = (u16*)(ws + oRD);
  u16* kvb  = (u16*)(ws + oRE);
  u16* attn_out = (u16*)(ws + oRE);
  u16* WqdT  = (u16*)(ws + oWqdT);
  u16* WkvdT = (u16*)(ws + oWkvdT);
  u16* WquT  = (u16*)(ws + oWquT);
  u16* WkvuT = (u16*)(ws + oWkvuT);
  u16* WoT   = (u16*)(ws + oWoT);

  cvt_f32_bf16<<<8192, 256, 0, stream>>>(hs, hs_bf, 2097152);
  dim3 tb(32, 8);
  transpose_f32_bf16<<<dim3(48, 64), tb, 0, stream>>>(Wqd, WqdT, 2048, 1536);
  transpose_f32_bf16<<<dim3(18, 64), tb, 0, stream>>>(Wkvd, WkvdT, 2048, 576);
  transpose_f32_bf16<<<dim3(96, 48), tb, 0, stream>>>(Wqu, WquT, 1536, 3072);
  transpose_f32_bf16<<<dim3(128, 16), tb, 0, stream>>>(Wkvu, WkvuT, 512, 4096);
  transpose_f32_bf16<<<dim3(64, 64), tb, 0, stream>>>(Wo, WoT, 2048, 2048);

  // q path
  gemm_bt<0><<<dim3(12, 32), 256, 0, stream>>>(hs_bf, WqdT, t1, 4096, 1536, 2048);
  rmsnorm_rows<<<4096, 256, 0, stream>>>(t1, qlat, 1536);
  gemm_bt<1><<<dim3(24, 32), 256, 0, stream>>>(qlat, WquT, q2, 4096, 3072, 1536);
  rope_pack_q<<<4096, 256, 0, stream>>>(q2, fc, fs, Qb);
  // kv path
  gemm_bt<0><<<dim3(5, 32), 256, 0, stream>>>(hs_bf, WkvdT, t3, 4096, 576, 2048);
  kv_split<<<4096, 256, 0, stream>>>(t3, fc, fs, kvl, krope);
  gemm_bt<1><<<dim3(32, 32), 256, 0, stream>>>(kvl, WkvuT, kvb, 4096, 4096, 512);
  assemble_kv2<<<dim3(256, 32), 256, 0, stream>>>(kvb, krope, Kc, Vt);
  // attention
  flash_attn<<<dim3(16, 32), 256, 0, stream>>>(Qb, Kc, Vt, attn_out);
  // output projection (fp32 out)
  gemm_bt<0><<<dim3(16, 32), 256, 0, stream>>>(attn_out, WoT, (float*)d_out, 4096, 2048, 2048);
}

// Round 4
// 586.203 us; speedup vs baseline: 12.1168x; 1.1275x over previous
//
#include <hip/hip_runtime.h>
#include <math.h>

// DeepSeekV3 MLA forward, MI355X gfx950.
// I/O fp32; internal GEMM/attention math bf16 MFMA. Balanced-pair flash attention.
// B=2 S=2048 D=2048 H=16 NOPE=128 ROPE=64 DV=128 DQK=192 QLR=1536 KVLR=512

typedef unsigned short u16;
typedef __attribute__((ext_vector_type(8))) __bf16 bf16x8;
typedef __attribute__((ext_vector_type(4))) float f32x4;

#define DEV static __device__ __forceinline__

DEV float b2f(u16 v) { return __uint_as_float(((unsigned int)v) << 16); }
DEV u16 f2b(float f) {
  unsigned int u = __float_as_uint(f);
  u += 0x7fffu + ((u >> 16) & 1u);   // round-to-nearest-even
  return (u16)(u >> 16);
}

DEV float waveReduceSum(float v) {
  #pragma unroll
  for (int o = 32; o > 0; o >>= 1) v += __shfl_down(v, o, 64);
  return v;
}

// async global->LDS, 16B per lane; LDS dest = wave-uniform base + lane*16
DEV void gld16(const u16* g, u16* l) {
  __builtin_amdgcn_global_load_lds((const __attribute__((address_space(1))) void*)g,
                                   (__attribute__((address_space(3))) void*)l, 16, 0, 0);
}

// ---------------- convert fp32 -> bf16 (flat) ----------------
__global__ __launch_bounds__(256)
void cvt_f32_bf16(const float* __restrict__ in, u16* __restrict__ out, int n4) {
  int i = blockIdx.x * 256 + threadIdx.x;
  if (i < n4) {
    float4 v = reinterpret_cast<const float4*>(in)[i];
    ushort4 o;
    o.x = f2b(v.x); o.y = f2b(v.y); o.z = f2b(v.z); o.w = f2b(v.w);
    reinterpret_cast<ushort4*>(out)[i] = o;
  }
}

// ---------------- transpose+convert: in f32 [R][C] -> out bf16 [C][R] ----------------
// out row stride = R (out may be a slice of a bigger [*][R] buffer)
__global__ __launch_bounds__(256)
void transpose_f32_bf16(const float* __restrict__ in, u16* __restrict__ out, int R, int C) {
  __shared__ u16 tile[32][33];
  int c0 = blockIdx.x * 32, r0 = blockIdx.y * 32;
  for (int i = threadIdx.y; i < 32; i += 8)
    tile[i][threadIdx.x] = f2b(in[(size_t)(r0 + i) * C + c0 + threadIdx.x]);
  __syncthreads();
  for (int i = threadIdx.y; i < 32; i += 8)
    out[(size_t)(c0 + i) * R + r0 + threadIdx.x] = tile[threadIdx.x][i];
}

// ---------------- MFMA bt-GEMM: C[M][N] = A[M][K] * BT[N][K]^T ----------------
template<int OUT_BF16>
__global__ __launch_bounds__(256)
void gemm_bt(const u16* __restrict__ A, const u16* __restrict__ BT, void* __restrict__ Cp,
             int M, int N, int K) {
  __shared__ __attribute__((aligned(16))) u16 As[4096];
  __shared__ __attribute__((aligned(16))) u16 Bs[4096];
  const int tid = threadIdx.x;
  const int lane = tid & 63;
  const int wave = tid >> 6;
  const int wm = (wave >> 1) * 64;
  const int wn = (wave & 1) * 64;
  const int q = lane >> 4;
  const int l16 = lane & 15;
  const int bm = blockIdx.y * 128;
  const int bn = blockIdx.x * 128;

  f32x4 zero = {0.f, 0.f, 0.f, 0.f};
  f32x4 acc[4][4];
  #pragma unroll
  for (int i = 0; i < 4; i++)
    #pragma unroll
    for (int j = 0; j < 4; j++) acc[i][j] = zero;

  for (int k0 = 0; k0 < K; k0 += 32) {
    #pragma unroll
    for (int i = 0; i < 2; i++) {
      int c = tid + i * 256;
      int m = c >> 2;
      int kq = c & 3;
      uint4 va = *reinterpret_cast<const uint4*>(A + (size_t)(bm + m) * K + k0 + kq * 8);
      *reinterpret_cast<uint4*>(As + (kq * 128 + m) * 8) = va;
      uint4 vb;
      if (bn + m < N)
        vb = *reinterpret_cast<const uint4*>(BT + (size_t)(bn + m) * K + k0 + kq * 8);
      else
        vb = make_uint4(0u, 0u, 0u, 0u);
      *reinterpret_cast<uint4*>(Bs + (kq * 128 + m) * 8) = vb;
    }
    __syncthreads();
    bf16x8 af[4], bfr[4];
    #pragma unroll
    for (int t = 0; t < 4; t++) {
      af[t]  = *reinterpret_cast<const bf16x8*>(As + (q * 128 + wm + t * 16 + l16) * 8);
      bfr[t] = *reinterpret_cast<const bf16x8*>(Bs + (q * 128 + wn + t * 16 + l16) * 8);
    }
    #pragma unroll
    for (int mt = 0; mt < 4; mt++)
      #pragma unroll
      for (int nt = 0; nt < 4; nt++)
        acc[mt][nt] = __builtin_amdgcn_mfma_f32_16x16x32_bf16(af[mt], bfr[nt], acc[mt][nt], 0, 0, 0);
    __syncthreads();
  }

  float* Cf = (float*)Cp;
  u16* Cb = (u16*)Cp;
  #pragma unroll
  for (int mt = 0; mt < 4; mt++) {
    #pragma unroll
    for (int nt = 0; nt < 4; nt++) {
      int col = bn + wn + nt * 16 + l16;
      if (col < N) {
        int row0 = bm + wm + mt * 16 + q * 4;
        #pragma unroll
        for (int r = 0; r < 4; r++) {
          size_t idx = (size_t)(row0 + r) * N + col;
          float v = acc[mt][nt][r];
          if (OUT_BF16) Cb[idx] = f2b(v); else Cf[idx] = v;
        }
      }
    }
  }
}

// ---------------- rmsnorm rows: fp32 [4096][stride] (first C cols) -> bf16 [4096][C] ----------------
__global__ __launch_bounds__(256)
void rmsnorm_rows(const float* __restrict__ in, u16* __restrict__ out, int C, int stride) {
  int row = blockIdx.x;
  const float* x = in + (size_t)row * stride;
  float ss = 0.f;
  for (int i = threadIdx.x; i < C; i += 256) { float v = x[i]; ss += v * v; }
  ss = waveReduceSum(ss);
  __shared__ float red[4];
  __shared__ float s_scale;
  int lane = threadIdx.x & 63, wid = threadIdx.x >> 6;
  if (lane == 0) red[wid] = ss;
  __syncthreads();
  if (threadIdx.x == 0)
    s_scale = rsqrtf((red[0] + red[1] + red[2] + red[3]) / (float)C + 1e-5f);
  __syncthreads();
  float sc = s_scale;
  u16* o = out + (size_t)row * C;
  for (int i = threadIdx.x; i < C; i += 256) o[i] = f2b(x[i] * sc);
}

// ---------------- rope + pack Q: q2 bf16 [B*S][H*192] -> Q bf16 [B*H][S][192] ----------------
__global__ __launch_bounds__(256)
void rope_pack_q(const u16* __restrict__ q2, const float* __restrict__ fc, const float* __restrict__ fs,
                 u16* __restrict__ Q) {
  int bs = blockIdx.x;
  int b = bs >> 11, s = bs & 2047;
  __shared__ float c[32], sn[32];
  if (threadIdx.x < 32) {
    c[threadIdx.x] = fc[s * 32 + threadIdx.x];
    sn[threadIdx.x] = fs[s * 32 + threadIdx.x];
  }
  __syncthreads();
  const u16* qrow = q2 + (size_t)bs * 3072;
  for (int t = threadIdx.x; t < 512; t += 256) {
    int h = t >> 5, i = t & 31;
    float x0 = b2f(qrow[h * 192 + 128 + 2 * i]);
    float x1 = b2f(qrow[h * 192 + 128 + 2 * i + 1]);
    size_t base = ((size_t)(b * 16 + h) * 2048 + s) * 192;
    Q[base + 2 * i]     = f2b(x0 * c[i] - x1 * sn[i]);
    Q[base + 2 * i + 1] = f2b(x0 * sn[i] + x1 * c[i]);
  }
  for (int t = threadIdx.x; t < 2048; t += 256) {
    int h = t >> 7, j = t & 127;
    Q[((size_t)(b * 16 + h) * 2048 + s) * 192 + 64 + j] = qrow[h * 192 + j];
  }
}

// ---------------- kv split: t13 fp32 [B*S][2112] cols 1536.. -> rmsnorm(kvl) + roped k_rope ----------------
__global__ __launch_bounds__(256)
void kv_split(const float* __restrict__ t13, const float* __restrict__ fc, const float* __restrict__ fs,
              u16* __restrict__ kvl, u16* __restrict__ krope) {
  int row = blockIdx.x;
  int s = row & 2047;
  const float* x = t13 + (size_t)row * 2112 + 1536;
  float ss = 0.f;
  for (int i = threadIdx.x; i < 512; i += 256) { float v = x[i]; ss += v * v; }
  ss = waveReduceSum(ss);
  __shared__ float red[4];
  __shared__ float s_scale;
  int lane = threadIdx.x & 63, wid = threadIdx.x >> 6;
  if (lane == 0) red[wid] = ss;
  __syncthreads();
  if (threadIdx.x == 0)
    s_scale = rsqrtf((red[0] + red[1] + red[2] + red[3]) * (1.0f / 512.0f) + 1e-5f);
  __syncthreads();
  float sc = s_scale;
  for (int i = threadIdx.x; i < 512; i += 256) kvl[(size_t)row * 512 + i] = f2b(x[i] * sc);
  if (threadIdx.x < 32) {
    int i = threadIdx.x;
    float cc = fc[s * 32 + i], sn = fs[s * 32 + i];
    float x0 = x[512 + 2 * i], x1 = x[512 + 2 * i + 1];
    krope[(size_t)row * 64 + 2 * i]     = f2b(x0 * cc - x1 * sn);
    krope[(size_t)row * 64 + 2 * i + 1] = f2b(x0 * sn + x1 * cc);
  }
}

// ---------------- assemble K chunked + V transposed chunked ----------------
// Kc[bh][kq 0..23][s 2048][8]  (dims kq*8..+7 of [rope64|nope128])
// Vt[bh][ks 0..255][dv 128][8] (keys ks*8..+7)
__global__ __launch_bounds__(256)
void assemble_kv2(const u16* __restrict__ kvb, const u16* __restrict__ krope,
                  u16* __restrict__ Kc, u16* __restrict__ Vt) {
  int ks = blockIdx.x;   // 0..255
  int bh = blockIdx.y;   // 0..31
  int b = bh >> 4, h = bh & 15;
  int t = threadIdx.x;
  if (t < 192) {
    int kq = t >> 3, sl = t & 7;
    int s = ks * 8 + sl;
    size_t bs = (size_t)(b * 2048 + s);
    uint4 v;
    if (kq < 8) v = *reinterpret_cast<const uint4*>(krope + bs * 64 + kq * 8);
    else        v = *reinterpret_cast<const uint4*>(kvb + bs * 4096 + h * 128 + (kq - 8) * 8);
    *reinterpret_cast<uint4*>(Kc + (((size_t)bh * 24 + kq) * 2048 + s) * 8) = v;
  }
  if (t < 128) {
    int dv = t;
    u16 tmp[8];
    #pragma unroll
    for (int j = 0; j < 8; j++) {
      int s = ks * 8 + j;
      tmp[j] = kvb[(size_t)(b * 2048 + s) * 4096 + 2048 + h * 128 + dv];
    }
    *reinterpret_cast<uint4*>(Vt + (((size_t)bh * 256 + ks) * 128 + dv) * 8) = *reinterpret_cast<uint4*>(tmp);
  }
}

// ---------------- MFMA flash attention, balanced pairs ----------------
// grid (16, 32): block handles q-tiles {t, 31-t} of 64 rows each -> uniform 33 k-tiles/block.
// 4 waves; wave owns 16 q-rows per tile; K-tile = 64 keys.
__global__ __launch_bounds__(256, 2)
void flash_attn2(const u16* __restrict__ Q, const u16* __restrict__ Kc,
                 const u16* __restrict__ Vt, u16* __restrict__ O) {
  __shared__ __attribute__((aligned(16))) u16 Ks[24 * 64 * 8];   // 24.5 KB [kq][key][8]
  __shared__ __attribute__((aligned(16))) u16 Vs[8 * 128 * 8];   // 16 KB  [kc][dv][8]
  __shared__ __attribute__((aligned(16))) u16 Ps[4 * 16 * 72];   // 9 KB   per-wave P, row stride 72

  const int tpair = blockIdx.x;      // 0..15
  const int bh = blockIdx.y;
  const int b = bh >> 4, h = bh & 15;
  const int tid = threadIdx.x, lane = tid & 63, wave = tid >> 6;
  const int quad = lane >> 4, l16 = lane & 15;
  const float scale = 0.07216878364870323f;  // 1/sqrt(192)
  u16* PsW = Ps + wave * 16 * 72;

  for (int phase = 0; phase < 2; phase++) {
    const int qt = phase == 0 ? tpair : 31 - tpair;
    const int q0 = qt * 64;
    const int nk = (qt + 1) * 64;

    // Q fragments in registers: rows q0 + wave*16 + l16
    bf16x8 qf[6];
    {
      int qrow = q0 + wave * 16 + l16;
      const u16* qp = Q + ((size_t)bh * 2048 + qrow) * 192 + quad * 8;
      #pragma unroll
      for (int kc = 0; kc < 6; kc++)
        qf[kc] = *reinterpret_cast<const bf16x8*>(qp + kc * 32);
    }

    f32x4 zero = {0.f, 0.f, 0.f, 0.f};
    f32x4 oacc[8];
    float m_run[4], l_run[4];
    #pragma unroll
    for (int nt = 0; nt < 8; nt++) oacc[nt] = zero;
    #pragma unroll
    for (int r = 0; r < 4; r++) { m_run[r] = -INFINITY; l_run[r] = 0.f; }

    for (int k0 = 0; k0 < nk; k0 += 64) {
      __syncthreads();   // prior iteration's LDS reads complete
      #pragma unroll
      for (int ii = 0; ii < 6; ii++) {
        int kq = wave * 6 + ii;
        gld16(Kc + (((size_t)bh * 24 + kq) * 2048 + k0 + lane) * 8, Ks + kq * 64 * 8);
      }
      #pragma unroll
      for (int jj = 0; jj < 4; jj++) {
        int vc = wave * 4 + jj;
        int kc = vc >> 1, dvh = vc & 1;
        gld16(Vt + (((size_t)bh * 256 + (k0 >> 3) + kc) * 128 + dvh * 64 + lane) * 8,
              Vs + (kc * 128 + dvh * 64) * 8);
      }
      __syncthreads();   // staging visible

      // QK^T
      f32x4 sacc[4];
      #pragma unroll
      for (int nt = 0; nt < 4; nt++) sacc[nt] = zero;
      #pragma unroll
      for (int kc = 0; kc < 6; kc++) {
        #pragma unroll
        for (int nt = 0; nt < 4; nt++) {
          bf16x8 kb = *reinterpret_cast<const bf16x8*>(Ks + ((kc * 4 + quad) * 64 + nt * 16 + l16) * 8);
          sacc[nt] = __builtin_amdgcn_mfma_f32_16x16x32_bf16(qf[kc], kb, sacc[nt], 0, 0, 0);
        }
      }

      // online softmax (rows quad*4+r; cols l16 within tile nt)
      #pragma unroll
      for (int r = 0; r < 4; r++) {
        int qrow_g = q0 + wave * 16 + quad * 4 + r;
        float sv[4];
        #pragma unroll
        for (int nt = 0; nt < 4; nt++) {
          int key = k0 + nt * 16 + l16;
          float v = sacc[nt][r] * scale;
          sv[nt] = (key <= qrow_g) ? v : -1e30f;
        }
        float mx = fmaxf(fmaxf(sv[0], sv[1]), fmaxf(sv[2], sv[3]));
        #pragma unroll
        for (int d = 1; d < 16; d <<= 1) mx = fmaxf(mx, __shfl_xor(mx, d, 64));
        float mold = m_run[r];
        float mnew = fmaxf(mold, mx);
        float alpha = __expf(mold - mnew);
        m_run[r] = mnew;
        float psum = 0.f;
        #pragma unroll
        for (int nt = 0; nt < 4; nt++) {
          float p = __expf(sv[nt] - mnew);
          psum += p;
          PsW[(quad * 4 + r) * 72 + nt * 16 + l16] = f2b(p);
        }
        #pragma unroll
        for (int d = 1; d < 16; d <<= 1) psum += __shfl_xor(psum, d, 64);
        l_run[r] = l_run[r] * alpha + psum;
        #pragma unroll
        for (int nt = 0; nt < 8; nt++) oacc[nt][r] *= alpha;
      }

      // PV: O += P Vtile (P in A-layout from wave-private LDS)
      #pragma unroll
      for (int kcp = 0; kcp < 2; kcp++) {
        bf16x8 pa = *reinterpret_cast<const bf16x8*>(PsW + l16 * 72 + kcp * 32 + quad * 8);
        #pragma unroll
        for (int nt = 0; nt < 8; nt++) {
          bf16x8 vb = *reinterpret_cast<const bf16x8*>(Vs + ((kcp * 4 + quad) * 128 + nt * 16 + l16) * 8);
          oacc[nt] = __builtin_amdgcn_mfma_f32_16x16x32_bf16(pa, vb, oacc[nt], 0, 0, 0);
        }
      }
    }

    // epilogue: O[b][s][h*128+dv] bf16
    float inv[4];
    #pragma unroll
    for (int r = 0; r < 4; r++) inv[r] = 1.0f / l_run[r];
    #pragma unroll
    for (int nt = 0; nt < 8; nt++) {
      #pragma unroll
      for (int r = 0; r < 4; r++) {
        int s = q0 + wave * 16 + quad * 4 + r;
        O[((size_t)b * 2048 + s) * 2048 + h * 128 + nt * 16 + l16] = f2b(oacc[nt][r] * inv[r]);
      }
    }
  }
}

// ---------------- launch ----------------
extern "C" void kernel_launch(void* const* d_in, const int* in_sizes, int n_in,
                              void* d_out, int out_size, void* d_ws, size_t ws_size,
                              hipStream_t stream) {
  (void)in_sizes; (void)n_in; (void)out_size; (void)ws_size;
  const float* hs   = (const float*)d_in[0];
  const float* fc   = (const float*)d_in[2];
  const float* fs   = (const float*)d_in[3];
  const float* Wqd  = (const float*)d_in[4];
  const float* Wkvd = (const float*)d_in[5];
  const float* Wqu  = (const float*)d_in[6];
  const float* Wkvu = (const float*)d_in[7];
  const float* Wo   = (const float*)d_in[8];

  char* ws = (char*)d_ws;
  size_t off = 0;
  auto alloc = [&](size_t bytes) { size_t o = off; off += (bytes + 255) & ~(size_t)255; return o; };
  const size_t oHS   = alloc(16777216);  // hs_bf bf16 [4096][2048]
  const size_t oRA   = alloc(16777216);  // Vt bf16 [32][256][128][8]
  const size_t oRB   = alloc(25165824);  // q2 bf16 [4096][3072] -> Kc bf16
  const size_t oRC   = alloc(12582912);  // qlat bf16 -> kvl bf16 + krope bf16
  const size_t oRD   = alloc(25165824);  // Q bf16 [B*H][S][192]
  const size_t oRE   = alloc(34603008);  // t13 f32 [4096][2112] -> kvb bf16 [4096][4096] -> attn_out
  const size_t oW13T  = alloc(8650752);  // [2112][2048] bf16 (WqdT rows 0..1535, WkvdT rows 1536..)
  const size_t oWquT  = alloc(9437184);
  const size_t oWkvuT = alloc(4194304);
  const size_t oWoT   = alloc(8388608);

  u16* hs_bf = (u16*)(ws + oHS);
  u16* Vt   = (u16*)(ws + oRA);
  u16* q2   = (u16*)(ws + oRB);
  u16* Kc   = (u16*)(ws + oRB);
  u16* qlat = (u16*)(ws + oRC);
  u16* kvl  = (u16*)(ws + oRC);
  u16* krope = (u16*)(ws + oRC + 4194304);
  u16* Qb   = (u16*)(ws + oRD);
  float* t13 = (float*)(ws + oRE);
  u16* kvb  = (u16*)(ws + oRE);
  u16* attn_out = (u16*)(ws + oRE);
  u16* W13T  = (u16*)(ws + oW13T);
  u16* WquT  = (u16*)(ws + oWquT);
  u16* WkvuT = (u16*)(ws + oWkvuT);
  u16* WoT   = (u16*)(ws + oWoT);

  cvt_f32_bf16<<<8192, 256, 0, stream>>>(hs, hs_bf, 2097152);
  dim3 tb(32, 8);
  transpose_f32_bf16<<<dim3(48, 64), tb, 0, stream>>>(Wqd, W13T, 2048, 1536);
  transpose_f32_bf16<<<dim3(18, 64), tb, 0, stream>>>(Wkvd, W13T + (size_t)1536 * 2048, 2048, 576);
  transpose_f32_bf16<<<dim3(96, 48), tb, 0, stream>>>(Wqu, WquT, 1536, 3072);
  transpose_f32_bf16<<<dim3(128, 16), tb, 0, stream>>>(Wkvu, WkvuT, 512, 4096);
  transpose_f32_bf16<<<dim3(64, 64), tb, 0, stream>>>(Wo, WoT, 2048, 2048);

  // fused down-projections: t13 = hs @ [Wq_down | Wkv_down]
  gemm_bt<0><<<dim3(17, 32), 256, 0, stream>>>(hs_bf, W13T, t13, 4096, 2112, 2048);
  // q path
  rmsnorm_rows<<<4096, 256, 0, stream>>>(t13, qlat, 1536, 2112);
  gemm_bt<1><<<dim3(24, 32), 256, 0, stream>>>(qlat, WquT, q2, 4096, 3072, 1536);
  rope_pack_q<<<4096, 256, 0, stream>>>(q2, fc, fs, Qb);
  // kv path
  kv_split<<<4096, 256, 0, stream>>>(t13, fc, fs, kvl, krope);
  gemm_bt<1><<<dim3(32, 32), 256, 0, stream>>>(kvl, WkvuT, kvb, 4096, 4096, 512);
  assemble_kv2<<<dim3(256, 32), 256, 0, stream>>>(kvb, krope, Kc, Vt);
  // attention
  flash_attn2<<<dim3(16, 32), 256, 0, stream>>>(Qb, Kc, Vt, attn_out);
  // output projection (fp32 out)
  gemm_bt<0><<<dim3(16, 32), 256, 0, stream>>>(attn_out, WoT, (float*)d_out, 4096, 2048, 2048);
}